// Round 15
// baseline (890.192 us; speedup 1.0000x reference)
//
#include <hip/hip_runtime.h>
#include <math.h>

#define NS 150
#define LDW 152
#define NPACK 11848   // packed upper-tri floats (rows 16B-aligned)
#define NT 40
#define MS 200
#define MT 30
#define N_SWEEPS 6
#define ROUNDS (N_SWEEPS*(NT-1))
#define JITTER 0.1f
#define NTHR 512
#define PREROW 45     // rows >= PREROW prefilled during jacobi; rs_off(45)=5916

// ---- LDS layout (bytes) ----
#define OFF_MP    0        // 47392
// jacobi overlay lives inside Mp[0 .. 14080) = packed offsets < 3520 floats,
// strictly below rs_off(PREROW)=5916 floats (23664 B) -> no clash w/ prefill
#define OFF_JA    0        // A 40x41x4 = 6560
#define OFF_JV    6560     // Vts 40x44x4 = 7040 -> 13600
#define OFF_JP    13600    // wprm 20x16 = 320 -> 13920
#define OFF_JT    13920    // tcs 160 -> 14080
#define OFF_PR    47392    // 8*152*4 = 4864 -> 52256
#define OFF_INVS  52256    // 32 -> 52288
#define OFF_DVS   52288    // 600 -> pad 52896
#define OFF_SCS   52896    // 1800 -> pad 54704
#define OFF_TSCS  54704    // 2400 -> 57104
#define OFF_QV    57104    // 800 -> 57904
#define OFF_RV    57904    // 800 -> 58704
#define OFF_GV    58704    // 600 -> 59304
#define OFF_ACOL  59304    // 120 -> 59424
#define OFF_WTJ   59424    // 4  -> 59428
#define SMEM_BYTES 59440

// packed upper-tri storage: row r holds cols [r&~3, 152), 16B-aligned start.
__device__ __forceinline__ int rs_off(int r) {
    int g = r >> 2, rm = r & 3;
    return LDW * r - 8 * g * (g - 1) - 4 * rm * g;
}

__device__ __forceinline__ void jac_params(const float (*A)[NT+1], float4* dst,
                                           int i, int rr) {
    int i0 = i, i1 = NT - 1 - i;
    int p = (i0 == 0) ? 0 : ((i0 - 1 + rr) % (NT - 1)) + 1;
    int q = ((i1 - 1 + rr) % (NT - 1)) + 1;
    if (p > q) { int tsw = p; p = q; q = tsw; }
    float app = A[p][p], aqq = A[q][q], apq = A[p][q];
    float c, s;
    if (apq == 0.0f) { c = 1.0f; s = 0.0f; }
    else {
        float tau = (aqq - app) / (2.0f * apq);
        float tt = ((tau >= 0.0f) ? 1.0f : -1.0f) / (fabsf(tau) + sqrtf(1.0f + tau*tau));
        c = rsqrtf(1.0f + tt*tt);
        s = tt * c;
    }
    dst[i] = make_float4(c, s, __int_as_float(p), __int_as_float(q));
}

// ONE kernel, 40 blocks x 512 threads. Wave 0 runs the 40x40 Jacobi SOLO
// (barrier-free: same-wave LDS in-order — mechanism proven R12-R14) while
// waves 1-7 prefill raw SE exponentials for packed rows >= PREROW. Then:
// extract (wt_j, g_j, Acol_j) -> build/scale M_j -> rank-8 panel factor
// (R14-proven) -> in-LDS scale -> fused trsm -> atomicAdd epilogue.
__global__ void __launch_bounds__(NTHR, 1) gp_block(
        const float* __restrict__ sc,  const float* __restrict__ tc,
        const float* __restrict__ st,  const float* __restrict__ tsc,
        const float* __restrict__ ttc,
        const float* __restrict__ lll, const float* __restrict__ lle,
        const float* __restrict__ llt, const float* __restrict__ lnv,
        const float* __restrict__ lsv, float* __restrict__ out) {
    __shared__ __align__(16) char smem[SMEM_BYTES];
    int j = blockIdx.x, tid = threadIdx.x;
    int wave = tid >> 6, lane = tid & 63;

    auto Aj   = (float (*)[NT+1])(smem + OFF_JA);
    auto Vts  = (float (*)[44])(smem + OFF_JV);
    float4* wp  = (float4*)(smem + OFF_JP);
    float* tcs  = (float*)(smem + OFF_JT);
    float* Mp   = (float*)(smem + OFF_MP);
    float* gv   = (float*)(smem + OFF_GV);
    float* Acol = (float*)(smem + OFF_ACOL);
    float* wtjs = (float*)(smem + OFF_WTJ);
    float* scs  = (float*)(smem + OFF_SCS);
    float* tscs = (float*)(smem + OFF_TSCS);

    float ilt2 = expf(-2.0f * llt[0]);
    float ill2 = expf(-2.0f * lll[0]);
    float ile2 = expf(-2.0f * lle[0]);
    if (tid < NT) tcs[tid] = tc[tid];
    for (int t = tid; t < NS*3; t += NTHR) scs[t] = sc[t];
    for (int t = tid; t < MS*3; t += NTHR) tscs[t] = tsc[t];
    __syncthreads();
    for (int idx = tid; idx < NT*NT; idx += NTHR) {
        int i = idx / NT, jj = idx - i*NT;
        float dt = tcs[i] - tcs[jj];
        float v = expf(-dt*dt*ilt2);
        if (i == jj) v += JITTER;
        Aj[i][jj] = v;
    }
    for (int idx = tid; idx < NT*44; idx += NTHR) {
        int jr = idx / 44, k = idx - jr*44;
        Vts[jr][k] = (jr == k) ? 1.0f : 0.0f;
    }
    __syncthreads();

    if (wave == 0) {
        // -------- solo-wave Jacobi: zero block barriers --------
        for (int rd = 0; rd < ROUNDS; ++rd) {
            int rr = rd % (NT - 1);
            if (lane < NT/2) jac_params(Aj, wp, lane, rr);
            __builtin_amdgcn_wave_barrier();   // pin order; wave LDS is in-order
            for (int t = lane; t < 400; t += 64) {
                int bi = t / 20, bj = t - bi*20;
                float4 Pi = wp[bi], Pj = wp[bj];
                int pi = __float_as_int(Pi.z), qi = __float_as_int(Pi.w);
                int pj = __float_as_int(Pj.z), qj = __float_as_int(Pj.w);
                float ci = Pi.x, si = Pi.y, cj = Pj.x, sj = Pj.y;
                float a00 = Aj[pi][pj], a01 = Aj[pi][qj];
                float a10 = Aj[qi][pj], a11 = Aj[qi][qj];
                float b00 = ci*a00 - si*a10, b01 = ci*a01 - si*a11;
                float b10 = si*a00 + ci*a10, b11 = si*a01 + ci*a11;
                Aj[pi][pj] = cj*b00 - sj*b01; Aj[pi][qj] = sj*b00 + cj*b01;
                Aj[qi][pj] = cj*b10 - sj*b11; Aj[qi][qj] = sj*b10 + cj*b11;
            }
            for (int t = lane; t < 200; t += 64) {
                int pr = t / 10, ch = (t - pr*10) << 2;
                float4 P = wp[pr];
                int pj = __float_as_int(P.z), qj = __float_as_int(P.w);
                float c = P.x, s = P.y;
                float4 vp = *(float4*)&Vts[pj][ch];
                float4 vq = *(float4*)&Vts[qj][ch];
                float4 np, nq;
                np.x = c*vp.x - s*vq.x; nq.x = s*vp.x + c*vq.x;
                np.y = c*vp.y - s*vq.y; nq.y = s*vp.y + c*vq.y;
                np.z = c*vp.z - s*vq.z; nq.z = s*vp.z + c*vq.z;
                np.w = c*vp.w - s*vq.w; nq.w = s*vp.w + c*vq.w;
                *(float4*)&Vts[pj][ch] = np;
                *(float4*)&Vts[qj][ch] = nq;
            }
            __builtin_amdgcn_wave_barrier();
        }
    } else {
        // -------- waves 1-7: prefill raw E for rows >= PREROW --------
        for (int idx = PREROW*LDW + (tid - 64); idx < NS*LDW; idx += NTHR - 64) {
            int r = idx / LDW, c = idx - r*LDW;
            int rbase = r & ~3;
            if (c < rbase || c >= NS) continue;
            float d0 = scs[r*3+0] - scs[c*3+0];
            float d1 = scs[r*3+1] - scs[c*3+1];
            float d2 = scs[r*3+2] - scs[c*3+2];
            Mp[rs_off(r) + c - rbase] =
                expf(-((d0*d0 + d1*d1)*ill2 + d2*d2*ile2));
        }
    }
    __syncthreads();

    // -------- extraction (overlay still intact) --------
    if (tid == 0) wtjs[0] = Aj[j][j];
    for (int s = tid; s < NS; s += NTHR) {
        const float4* va = (const float4*)&Vts[j][0];
        const float4* sa = (const float4*)&st[s*NT];
        float acc = 0.0f;
        #pragma unroll
        for (int c4 = 0; c4 < NT/4; ++c4) {
            float4 a = va[c4], b = sa[c4];
            acc += a.x*b.x + a.y*b.y + a.z*b.z + a.w*b.w;
        }
        gv[s] = acc;
    }
    if (tid < MT) {
        float ttv = ttc[tid];
        float acc = 0.0f;
        for (int t = 0; t < NT; ++t) {
            float dt = ttv - tcs[t];
            acc += expf(-dt*dt*ilt2) * Vts[j][t];
        }
        Acol[tid] = acc;
    }
    __syncthreads();

    // -------- build rows < PREROW, scale rows >= PREROW, RHS col --------
    float wtj = wtjs[0];
    float nv = expf(lnv[0]);
    for (int idx = tid; idx < NS*LDW; idx += NTHR) {
        int r = idx / LDW, c = idx - r*LDW;
        int rbase = r & ~3;
        if (c < rbase) continue;
        int t = rs_off(r) + c - rbase;
        if (c == NS) { Mp[t] = gv[r]; continue; }
        if (c > NS)  { Mp[t] = 0.0f; continue; }
        float v;
        if (r < PREROW) {
            float d0 = scs[r*3+0] - scs[c*3+0];
            float d1 = scs[r*3+1] - scs[c*3+1];
            float d2 = scs[r*3+2] - scs[c*3+2];
            v = wtj * expf(-((d0*d0 + d1*d1)*ill2 + d2*d2*ile2));
        } else {
            v = wtj * Mp[t];               // prefilled raw E
        }
        if (c == r) v += wtj * JITTER + nv;
        Mp[t] = v;
    }
    __syncthreads();

    // -------- rank-8 panel factorization (R14-proven) --------
    auto   Pr   = (float (*)[LDW])(smem + OFF_PR);
    float* invs = (float*)(smem + OFF_INVS);
    float* dvs  = (float*)(smem + OFF_DVS);
    float* qv   = (float*)(smem + OFF_QV);
    float* Rv   = (float*)(smem + OFF_RV);
    for (int k0 = 0; k0 < NS - 1; k0 += 8) {
        int P = NS - k0; if (P > 8) P = 8;
        int W4 = (LDW - k0) >> 2;
        if (tid < W4) {
            int off[8];
            #pragma unroll
            for (int i = 0; i < 8; ++i)
                off[i] = (i < P) ? (rs_off(k0 + i) - ((i >= 4) ? 4 : 0)) : 0;
            float Bm[8][8];
            #pragma unroll
            for (int i = 0; i < 8; ++i) {
                #pragma unroll
                for (int c = 0; c < 8; ++c)
                    Bm[i][c] = (i < P && c >= i) ? Mp[off[i] + c]
                                                 : ((c == i) ? 1.0f : 0.0f);
            }
            float Lf[8][8]; float iv[8];
            #pragma unroll
            for (int k = 0; k < 8; ++k) {
                iv[k] = 1.0f / Bm[k][k];
                #pragma unroll
                for (int i = k + 1; i < 8; ++i) {
                    float l = Bm[k][i] * iv[k];
                    Lf[i][k] = l;
                    #pragma unroll
                    for (int c = i; c < 8; ++c) Bm[i][c] -= l * Bm[k][c];
                }
            }
            if (tid == 0) {
                #pragma unroll
                for (int i = 0; i < 8; ++i) invs[i] = iv[i];
            }
            int C = tid << 2;
            float4 m[8];
            #pragma unroll
            for (int i = 0; i < 8; ++i) {
                bool ok = (i < P) && (i < 4 || C >= 4);
                m[i] = ok ? *(float4*)&Mp[off[i] + C] : make_float4(0,0,0,0);
            }
            #pragma unroll
            for (int i = 1; i < 8; ++i) {
                #pragma unroll
                for (int k = 0; k < i; ++k) {
                    float l = Lf[i][k];
                    m[i].x -= l*m[k].x; m[i].y -= l*m[k].y;
                    m[i].z -= l*m[k].z; m[i].w -= l*m[k].w;
                }
            }
            #pragma unroll
            for (int i = 0; i < 8; ++i) *(float4*)&Pr[i][C] = m[i];
        }
        __syncthreads();
        for (int r = k0 + 1 + tid; r < NS; r += NTHR) {
            int rc = r - k0;
            float f[8];
            #pragma unroll
            for (int i = 0; i < 8; ++i)
                f[i] = (rc > i && i < P) ? Pr[i][rc] * invs[i] : 0.0f;
            int rbase = r & ~3;
            int ro = rs_off(r) - rbase;
            for (int C = rbase; C < LDW; C += 4) {
                int pc = C - k0;
                float4 v = *(float4*)&Mp[ro + C];
                #pragma unroll
                for (int i = 0; i < 8; ++i) {
                    float4 p = *(float4*)&Pr[i][pc];
                    v.x -= f[i]*p.x; v.y -= f[i]*p.y;
                    v.z -= f[i]*p.z; v.w -= f[i]*p.w;
                }
                *(float4*)&Mp[ro + C] = v;
            }
        }
        __syncthreads();
    }
    // scale in place: diag slot = 1/d, cols>r (incl. RHS col 150 -> y) *= 1/d
    for (int r = tid; r < NS; r += NTHR)
        dvs[r] = rsqrtf(Mp[rs_off(r) + r - (r & ~3)]);
    __syncthreads();
    for (int idx = tid; idx < NS*LDW; idx += NTHR) {
        int r = idx / LDW, c = idx - r*LDW;
        int rbase = r & ~3;
        if (c < rbase) continue;
        int t = rs_off(r) + c - rbase;
        float dvr = dvs[r];
        if (c == r) Mp[t] = dvr;
        else if (c > r) Mp[t] *= dvr;
    }
    __syncthreads();
    // fused trsm: thread-per-test-column, u[] in registers (152 w/ zero tail)
    if (tid < MS) {
        float tx = tscs[tid*3+0], ty = tscs[tid*3+1], tz = tscs[tid*3+2];
        float u[LDW];
        #pragma unroll
        for (int k = 0; k < NS; ++k) {
            float d0 = tx - scs[k*3+0];
            float d1 = ty - scs[k*3+1];
            float d2 = tz - scs[k*3+2];
            u[k] = expf(-((d0*d0 + d1*d1)*ill2 + d2*d2*ile2));
        }
        u[150] = 0.0f; u[151] = 0.0f;
        float qa = 0.0f, ra = 0.0f;
        #pragma unroll
        for (int k = 0; k < NS; ++k) {
            const int base = rs_off(k) - (k & ~3);
            float uk = u[k] * Mp[base + k];     // diag slot = 1/d
            qa += uk * uk;
            ra += uk * Mp[base + 150];          // scaled RHS = y_k
            const int kp = k + 1;
            const int ka = (kp + 3) & ~3;
            #pragma unroll
            for (int t = kp; t < ((ka < NS) ? ka : NS); ++t)
                u[t] -= Mp[base + t] * uk;
            #pragma unroll
            for (int t = ka; t < NS; t += 4) {
                float4 w = *(const float4*)&Mp[base + t];
                u[t+0] -= w.x * uk; u[t+1] -= w.y * uk;
                u[t+2] -= w.z * uk; u[t+3] -= w.w * uk;
            }
        }
        qv[tid] = qa;
        Rv[tid] = ra;
    }
    __syncthreads();

    // -------- atomic rank-1 accumulation into pre-zeroed out --------
    float sigv = expf(lsv[0]);
    for (int idx = tid; idx < MS*MT; idx += NTHR) {
        int is = idx / MT, it = idx - is*MT;
        float a = Acol[it];
        atomicAdd(&out[idx], a * Rv[is]);
        float c2 = -a * a * qv[is];
        if (j == 0) c2 += sigv;
        atomicAdd(&out[MS*MT + idx], c2);
    }
}

extern "C" void kernel_launch(void* const* d_in, const int* in_sizes, int n_in,
                              void* d_out, int out_size, void* d_ws, size_t ws_size,
                              hipStream_t stream) {
    const float* sc  = (const float*)d_in[0];   // 150x3
    const float* tc  = (const float*)d_in[1];   // 40x1
    const float* st  = (const float*)d_in[2];   // 150x40
    const float* tsc = (const float*)d_in[3];   // 200x3
    const float* ttc = (const float*)d_in[4];   // 30x1
    const float* lll = (const float*)d_in[5];
    const float* lle = (const float*)d_in[6];
    const float* llt = (const float*)d_in[7];
    const float* lnv = (const float*)d_in[8];
    const float* lsv = (const float*)d_in[9];
    float* out = (float*)d_out;

    hipMemsetAsync(out, 0, (size_t)out_size * sizeof(float), stream);
    hipLaunchKernelGGL(gp_block, dim3(NT), dim3(NTHR), 0, stream,
                       sc, tc, st, tsc, ttc, lll, lle, llt, lnv, lsv, out);
}

// Round 16
// 450.081 us; speedup vs baseline: 1.9778x; 1.9778x over previous
//
#include <hip/hip_runtime.h>
#include <math.h>

#define NS 150
#define LDW 152
#define NPACK 11848   // packed upper-tri floats (rows 16B-aligned)
#define NT 40
#define MS 200
#define MT 30
#define N_SWEEPS 6
#define ROUNDS (N_SWEEPS*(NT-1))
#define JITTER 0.1f
#define NTHR 512
#define PREROW 45     // rows >= PREROW prefilled during jacobi; rs_off(45)=5916
#define PF_LO (PREROW*LDW)      // 6840
#define PF_HI (NS*LDW)          // 22800
#define PF_CH 69                // ceil((PF_HI-PF_LO)/ROUNDS)

// ---- LDS layout (bytes) ----
#define OFF_MP    0        // 47392
// jacobi overlay inside Mp[0..14080 B) = packed floats < 3520,
// strictly below rs_off(PREROW)=5916 floats (23664 B) -> disjoint from prefill
#define OFF_JA    0        // A 40x41x4 = 6560
#define OFF_JV    6560     // Vts 40x44x4 = 7040 -> 13600
#define OFF_JP    13600    // prm 2 bufs unused; per-wave prm 8*20*16=2560 -> 16160
#define OFF_JT    16160    // tcs 160 -> 16320
#define OFF_PR    47392    // 8*152*4 = 4864 -> 52256
#define OFF_INVS  52256    // 32 -> 52288
#define OFF_DVS   52288    // 600 -> pad 52896
#define OFF_SCS   52896    // 1800 -> pad 54704
#define OFF_TSCS  54704    // 2400 -> 57104
#define OFF_QV    57104    // 800 -> 57904
#define OFF_RV    57904    // 800 -> 58704
#define OFF_GV    58704    // 600 -> 59304
#define OFF_ACOL  59304    // 120 -> 59424
#define OFF_WTJ   59424    // 4  -> 59428
#define SMEM_BYTES 59440

// packed upper-tri storage: row r holds cols [r&~3, 152), 16B-aligned start.
__device__ __forceinline__ int rs_off(int r) {
    int g = r >> 2, rm = r & 3;
    return LDW * r - 8 * g * (g - 1) - 4 * rm * g;
}

__device__ __forceinline__ void jac_params(const float (*A)[NT+1], float4* dst,
                                           int i, int rr) {
    int i0 = i, i1 = NT - 1 - i;
    int p = (i0 == 0) ? 0 : ((i0 - 1 + rr) % (NT - 1)) + 1;
    int q = ((i1 - 1 + rr) % (NT - 1)) + 1;
    if (p > q) { int tsw = p; p = q; q = tsw; }
    float app = A[p][p], aqq = A[q][q], apq = A[p][q];
    float c, s;
    if (apq == 0.0f) { c = 1.0f; s = 0.0f; }
    else {
        float tau = (aqq - app) / (2.0f * apq);
        float tt = ((tau >= 0.0f) ? 1.0f : -1.0f) / (fabsf(tau) + sqrtf(1.0f + tau*tau));
        c = rsqrtf(1.0f + tt*tt);
        s = tt * c;
    }
    dst[i] = make_float4(c, s, __int_as_float(p), __int_as_float(q));
}

// ONE kernel, 40 blocks x 512 threads (R14-proven structure). Per block:
// all-wave Jacobi (1 barrier/round, per-wave redundant params) WITH raw-E
// prefill slices folded into each round (R15-proven logic, disjoint LDS);
// extract (wt_j, g_j, Acol_j); split M-build (compute rows<PREROW, scale
// prefilled rows>=PREROW); rank-8 panel factor; in-LDS scale; fused trsm;
// atomicAdd rank-1 epilogue into pre-zeroed out.
__global__ void __launch_bounds__(NTHR, 1) gp_block(
        const float* __restrict__ sc,  const float* __restrict__ tc,
        const float* __restrict__ st,  const float* __restrict__ tsc,
        const float* __restrict__ ttc,
        const float* __restrict__ lll, const float* __restrict__ lle,
        const float* __restrict__ llt, const float* __restrict__ lnv,
        const float* __restrict__ lsv, float* __restrict__ out) {
    __shared__ __align__(16) char smem[SMEM_BYTES];
    int j = blockIdx.x, tid = threadIdx.x;
    int wave = tid >> 6, lane = tid & 63;

    auto Aj   = (float (*)[NT+1])(smem + OFF_JA);
    auto Vts  = (float (*)[44])(smem + OFF_JV);
    auto prm  = (float4 (*)[NT/2])(smem + OFF_JP);
    float* tcs  = (float*)(smem + OFF_JT);
    float* Mp   = (float*)(smem + OFF_MP);
    float* gv   = (float*)(smem + OFF_GV);
    float* Acol = (float*)(smem + OFF_ACOL);
    float* wtjs = (float*)(smem + OFF_WTJ);
    float* scs  = (float*)(smem + OFF_SCS);
    float* tscs = (float*)(smem + OFF_TSCS);

    float ilt2 = expf(-2.0f * llt[0]);
    float ill2 = expf(-2.0f * lll[0]);
    float ile2 = expf(-2.0f * lle[0]);
    if (tid < NT) tcs[tid] = tc[tid];
    for (int t = tid; t < NS*3; t += NTHR) scs[t] = sc[t];
    for (int t = tid; t < MS*3; t += NTHR) tscs[t] = tsc[t];
    __syncthreads();
    for (int idx = tid; idx < NT*NT; idx += NTHR) {
        int i = idx / NT, jj = idx - i*NT;
        float dt = tcs[i] - tcs[jj];
        float v = expf(-dt*dt*ilt2);
        if (i == jj) v += JITTER;
        Aj[i][jj] = v;
    }
    for (int idx = tid; idx < NT*44; idx += NTHR) {
        int jr = idx / 44, k = idx - jr*44;
        Vts[jr][k] = (jr == k) ? 1.0f : 0.0f;
    }
    __syncthreads();

    // -------- all-wave Jacobi, 1 barrier/round, + prefill slice --------
    for (int rd = 0; rd < ROUNDS; ++rd) {
        float4* wp = prm[wave];
        if (lane < NT/2) jac_params(Aj, wp, lane, rd % (NT - 1));
        __builtin_amdgcn_wave_barrier();   // same-wave LDS in-order; pin compiler
        for (int t = tid; t < 600; t += NTHR) {
            if (t < 400) {
                int bi = t / 20, bj = t - bi*20;
                float4 Pi = wp[bi], Pj = wp[bj];
                int pi = __float_as_int(Pi.z), qi = __float_as_int(Pi.w);
                int pj = __float_as_int(Pj.z), qj = __float_as_int(Pj.w);
                float ci = Pi.x, si = Pi.y, cj = Pj.x, sj = Pj.y;
                float a00 = Aj[pi][pj], a01 = Aj[pi][qj];
                float a10 = Aj[qi][pj], a11 = Aj[qi][qj];
                float b00 = ci*a00 - si*a10, b01 = ci*a01 - si*a11;
                float b10 = si*a00 + ci*a10, b11 = si*a01 + ci*a11;
                Aj[pi][pj] = cj*b00 - sj*b01; Aj[pi][qj] = sj*b00 + cj*b01;
                Aj[qi][pj] = cj*b10 - sj*b11; Aj[qi][qj] = sj*b10 + cj*b11;
            } else {
                int u2 = t - 400;
                int pr = u2 / 10, ch = (u2 - pr*10) << 2;
                float4 P = wp[pr];
                int pj = __float_as_int(P.z), qj = __float_as_int(P.w);
                float c = P.x, s = P.y;
                float4 vp = *(float4*)&Vts[pj][ch];
                float4 vq = *(float4*)&Vts[qj][ch];
                float4 np, nq;
                np.x = c*vp.x - s*vq.x; nq.x = s*vp.x + c*vq.x;
                np.y = c*vp.y - s*vq.y; nq.y = s*vp.y + c*vq.y;
                np.z = c*vp.z - s*vq.z; nq.z = s*vp.z + c*vq.z;
                np.w = c*vp.w - s*vq.w; nq.w = s*vp.w + c*vq.w;
                *(float4*)&Vts[pj][ch] = np;
                *(float4*)&Vts[qj][ch] = nq;
            }
        }
        // prefill slice: raw SE exps for packed rows >= PREROW (disjoint LDS)
        if (tid < PF_CH) {
            int idx = PF_LO + rd * PF_CH + tid;
            if (idx < PF_HI) {
                int r = idx / LDW, c = idx - r*LDW;
                int rbase = r & ~3;
                if (c >= rbase && c < NS) {
                    float d0 = scs[r*3+0] - scs[c*3+0];
                    float d1 = scs[r*3+1] - scs[c*3+1];
                    float d2 = scs[r*3+2] - scs[c*3+2];
                    Mp[rs_off(r) + c - rbase] =
                        expf(-((d0*d0 + d1*d1)*ill2 + d2*d2*ile2));
                }
            }
        }
        __syncthreads();
    }

    // -------- extraction --------
    if (tid == 0) wtjs[0] = Aj[j][j];
    for (int s = tid; s < NS; s += NTHR) {
        const float4* va = (const float4*)&Vts[j][0];
        const float4* sa = (const float4*)&st[s*NT];
        float acc = 0.0f;
        #pragma unroll
        for (int c4 = 0; c4 < NT/4; ++c4) {
            float4 a = va[c4], b = sa[c4];
            acc += a.x*b.x + a.y*b.y + a.z*b.z + a.w*b.w;
        }
        gv[s] = acc;
    }
    if (tid < MT) {
        float ttv = ttc[tid];
        float acc = 0.0f;
        for (int t = 0; t < NT; ++t) {
            float dt = ttv - tcs[t];
            acc += expf(-dt*dt*ilt2) * Vts[j][t];
        }
        Acol[tid] = acc;
    }
    __syncthreads();

    // -------- build rows < PREROW, scale rows >= PREROW, RHS col --------
    float wtj = wtjs[0];
    float nv = expf(lnv[0]);
    for (int idx = tid; idx < NS*LDW; idx += NTHR) {
        int r = idx / LDW, c = idx - r*LDW;
        int rbase = r & ~3;
        if (c < rbase) continue;
        int t = rs_off(r) + c - rbase;
        if (c == NS) { Mp[t] = gv[r]; continue; }
        if (c > NS)  { Mp[t] = 0.0f; continue; }
        float v;
        if (r < PREROW) {
            float d0 = scs[r*3+0] - scs[c*3+0];
            float d1 = scs[r*3+1] - scs[c*3+1];
            float d2 = scs[r*3+2] - scs[c*3+2];
            v = wtj * expf(-((d0*d0 + d1*d1)*ill2 + d2*d2*ile2));
        } else {
            v = wtj * Mp[t];               // prefilled raw E
        }
        if (c == r) v += wtj * JITTER + nv;
        Mp[t] = v;
    }
    __syncthreads();

    // -------- rank-8 panel factorization (R14-proven) --------
    auto   Pr   = (float (*)[LDW])(smem + OFF_PR);
    float* invs = (float*)(smem + OFF_INVS);
    float* dvs  = (float*)(smem + OFF_DVS);
    float* qv   = (float*)(smem + OFF_QV);
    float* Rv   = (float*)(smem + OFF_RV);
    for (int k0 = 0; k0 < NS - 1; k0 += 8) {
        int P = NS - k0; if (P > 8) P = 8;
        int W4 = (LDW - k0) >> 2;
        if (tid < W4) {
            int off[8];
            #pragma unroll
            for (int i = 0; i < 8; ++i)
                off[i] = (i < P) ? (rs_off(k0 + i) - ((i >= 4) ? 4 : 0)) : 0;
            float Bm[8][8];
            #pragma unroll
            for (int i = 0; i < 8; ++i) {
                #pragma unroll
                for (int c = 0; c < 8; ++c)
                    Bm[i][c] = (i < P && c >= i) ? Mp[off[i] + c]
                                                 : ((c == i) ? 1.0f : 0.0f);
            }
            float Lf[8][8]; float iv[8];
            #pragma unroll
            for (int k = 0; k < 8; ++k) {
                iv[k] = 1.0f / Bm[k][k];
                #pragma unroll
                for (int i = k + 1; i < 8; ++i) {
                    float l = Bm[k][i] * iv[k];
                    Lf[i][k] = l;
                    #pragma unroll
                    for (int c = i; c < 8; ++c) Bm[i][c] -= l * Bm[k][c];
                }
            }
            if (tid == 0) {
                #pragma unroll
                for (int i = 0; i < 8; ++i) invs[i] = iv[i];
            }
            int C = tid << 2;
            float4 m[8];
            #pragma unroll
            for (int i = 0; i < 8; ++i) {
                bool ok = (i < P) && (i < 4 || C >= 4);
                m[i] = ok ? *(float4*)&Mp[off[i] + C] : make_float4(0,0,0,0);
            }
            #pragma unroll
            for (int i = 1; i < 8; ++i) {
                #pragma unroll
                for (int k = 0; k < i; ++k) {
                    float l = Lf[i][k];
                    m[i].x -= l*m[k].x; m[i].y -= l*m[k].y;
                    m[i].z -= l*m[k].z; m[i].w -= l*m[k].w;
                }
            }
            #pragma unroll
            for (int i = 0; i < 8; ++i) *(float4*)&Pr[i][C] = m[i];
        }
        __syncthreads();
        for (int r = k0 + 1 + tid; r < NS; r += NTHR) {
            int rc = r - k0;
            float f[8];
            #pragma unroll
            for (int i = 0; i < 8; ++i)
                f[i] = (rc > i && i < P) ? Pr[i][rc] * invs[i] : 0.0f;
            int rbase = r & ~3;
            int ro = rs_off(r) - rbase;
            for (int C = rbase; C < LDW; C += 4) {
                int pc = C - k0;
                float4 v = *(float4*)&Mp[ro + C];
                #pragma unroll
                for (int i = 0; i < 8; ++i) {
                    float4 p = *(float4*)&Pr[i][pc];
                    v.x -= f[i]*p.x; v.y -= f[i]*p.y;
                    v.z -= f[i]*p.z; v.w -= f[i]*p.w;
                }
                *(float4*)&Mp[ro + C] = v;
            }
        }
        __syncthreads();
    }
    // scale in place: diag slot = 1/d, cols>r (incl. RHS col 150 -> y) *= 1/d
    for (int r = tid; r < NS; r += NTHR)
        dvs[r] = rsqrtf(Mp[rs_off(r) + r - (r & ~3)]);
    __syncthreads();
    for (int idx = tid; idx < NS*LDW; idx += NTHR) {
        int r = idx / LDW, c = idx - r*LDW;
        int rbase = r & ~3;
        if (c < rbase) continue;
        int t = rs_off(r) + c - rbase;
        float dvr = dvs[r];
        if (c == r) Mp[t] = dvr;
        else if (c > r) Mp[t] *= dvr;
    }
    __syncthreads();
    // fused trsm: thread-per-test-column, u[] in registers (152 w/ zero tail)
    if (tid < MS) {
        float tx = tscs[tid*3+0], ty = tscs[tid*3+1], tz = tscs[tid*3+2];
        float u[LDW];
        #pragma unroll
        for (int k = 0; k < NS; ++k) {
            float d0 = tx - scs[k*3+0];
            float d1 = ty - scs[k*3+1];
            float d2 = tz - scs[k*3+2];
            u[k] = expf(-((d0*d0 + d1*d1)*ill2 + d2*d2*ile2));
        }
        u[150] = 0.0f; u[151] = 0.0f;
        float qa = 0.0f, ra = 0.0f;
        #pragma unroll
        for (int k = 0; k < NS; ++k) {
            const int base = rs_off(k) - (k & ~3);
            float uk = u[k] * Mp[base + k];     // diag slot = 1/d
            qa += uk * uk;
            ra += uk * Mp[base + 150];          // scaled RHS = y_k
            const int kp = k + 1;
            const int ka = (kp + 3) & ~3;
            #pragma unroll
            for (int t = kp; t < ((ka < NS) ? ka : NS); ++t)
                u[t] -= Mp[base + t] * uk;
            #pragma unroll
            for (int t = ka; t < NS; t += 4) {
                float4 w = *(const float4*)&Mp[base + t];
                u[t+0] -= w.x * uk; u[t+1] -= w.y * uk;
                u[t+2] -= w.z * uk; u[t+3] -= w.w * uk;
            }
        }
        qv[tid] = qa;
        Rv[tid] = ra;
    }
    __syncthreads();

    // -------- atomic rank-1 accumulation into pre-zeroed out --------
    float sigv = expf(lsv[0]);
    for (int idx = tid; idx < MS*MT; idx += NTHR) {
        int is = idx / MT, it = idx - is*MT;
        float a = Acol[it];
        atomicAdd(&out[idx], a * Rv[is]);
        float c2 = -a * a * qv[is];
        if (j == 0) c2 += sigv;
        atomicAdd(&out[MS*MT + idx], c2);
    }
}

extern "C" void kernel_launch(void* const* d_in, const int* in_sizes, int n_in,
                              void* d_out, int out_size, void* d_ws, size_t ws_size,
                              hipStream_t stream) {
    const float* sc  = (const float*)d_in[0];   // 150x3
    const float* tc  = (const float*)d_in[1];   // 40x1
    const float* st  = (const float*)d_in[2];   // 150x40
    const float* tsc = (const float*)d_in[3];   // 200x3
    const float* ttc = (const float*)d_in[4];   // 30x1
    const float* lll = (const float*)d_in[5];
    const float* lle = (const float*)d_in[6];
    const float* llt = (const float*)d_in[7];
    const float* lnv = (const float*)d_in[8];
    const float* lsv = (const float*)d_in[9];
    float* out = (float*)d_out;

    hipMemsetAsync(out, 0, (size_t)out_size * sizeof(float), stream);
    hipLaunchKernelGGL(gp_block, dim3(NT), dim3(NTHR), 0, stream,
                       sc, tc, st, tsc, ttc, lll, lle, llt, lnv, lsv, out);
}

// Round 17
// 418.122 us; speedup vs baseline: 2.1290x; 1.0764x over previous
//
#include <hip/hip_runtime.h>
#include <math.h>

#define NS 150
#define LDW 152
#define NPACK 11848   // packed upper-tri floats (rows 16B-aligned)
#define NT 40
#define MS 200
#define MT 30
#define N_SWEEPS 6
#define ROUNDS (N_SWEEPS*(NT-1))
#define JITTER 0.1f
#define NTHR 512

// ---- LDS union layout (bytes) ----
#define OFF_MP    0        // 47392
#define OFF_PR    47392    // 8*152*4 = 4864 -> 52256
#define OFF_INVS  52256    // 32 -> 52288
#define OFF_DVS   52288    // 600 -> 52896 (pad)
#define OFF_SCS   52896    // 1800 -> 54704 (pad)
#define OFF_TSCS  54704    // 2400 -> 57104
#define OFF_QV    57104    // 800 -> 57904
#define OFF_RV    57904    // 800 -> 58704
#define OFF_GV    58704    // 600 -> 59304
#define OFF_ACOL  59304    // 120 -> 59424
#define OFF_WTJ   59424    // 4  -> 59428
#define SMEM_BYTES 59440
// jacobi-phase overlay (inside Mp region only):
#define OFF_A2    0        // 2*40*41*4 = 13120
#define OFF_VTS   13120    // 40*44*4 = 7040 -> 20160
#define OFF_PRM   20160    // 8*20*16 = 2560 -> 22720
#define OFF_TCS   22720    // 160 -> 22880   (< OFF_PR; gv/Acol/wtj live above)

// packed upper-tri storage: row r holds cols [r&~3, 152), 16B-aligned start.
__device__ __forceinline__ int rs_off(int r) {
    int g = r >> 2, rm = r & 3;
    return LDW * r - 8 * g * (g - 1) - 4 * rm * g;
}

__device__ __forceinline__ void jac_params(const float (*A)[NT+1], float4* dst,
                                           int i, int rr) {
    int i0 = i, i1 = NT - 1 - i;
    int p = (i0 == 0) ? 0 : ((i0 - 1 + rr) % (NT - 1)) + 1;
    int q = ((i1 - 1 + rr) % (NT - 1)) + 1;
    if (p > q) { int tsw = p; p = q; q = tsw; }
    float app = A[p][p], aqq = A[q][q], apq = A[p][q];
    float c, s;
    if (apq == 0.0f) { c = 1.0f; s = 0.0f; }
    else {
        float tau = (aqq - app) / (2.0f * apq);
        float tt = ((tau >= 0.0f) ? 1.0f : -1.0f) / (fabsf(tau) + sqrtf(1.0f + tau*tau));
        c = rsqrtf(1.0f + tt*tt);
        s = tt * c;
    }
    dst[i] = make_float4(c, s, __int_as_float(p), __int_as_float(q));
}

// ONE kernel, 40 blocks x 512 threads (R14 configuration — best measured).
// Per block: redundant Jacobi (1 barrier/round, per-wave redundant params,
// all 8 waves participate) -> extract (wt_j, g_j, Acol_j) -> packed M_j
// build -> rank-8 panel factorization -> in-LDS scale -> fused trsm ->
// atomicAdd rank-1 epilogue into pre-zeroed out.
__global__ void __launch_bounds__(NTHR, 1) gp_block(
        const float* __restrict__ sc,  const float* __restrict__ tc,
        const float* __restrict__ st,  const float* __restrict__ tsc,
        const float* __restrict__ ttc,
        const float* __restrict__ lll, const float* __restrict__ lle,
        const float* __restrict__ llt, const float* __restrict__ lnv,
        const float* __restrict__ lsv, float* __restrict__ out) {
    __shared__ __align__(16) char smem[SMEM_BYTES];
    int j = blockIdx.x, tid = threadIdx.x;

    auto A2   = (float (*)[NT][NT+1])(smem + OFF_A2);
    auto Vts  = (float (*)[44])(smem + OFF_VTS);
    auto prm  = (float4 (*)[NT/2])(smem + OFF_PRM);
    float* tcs  = (float*)(smem + OFF_TCS);
    float* gv   = (float*)(smem + OFF_GV);
    float* Acol = (float*)(smem + OFF_ACOL);
    float* wtjs = (float*)(smem + OFF_WTJ);
    float* scs  = (float*)(smem + OFF_SCS);
    float* tscs = (float*)(smem + OFF_TSCS);

    float ilt2 = expf(-2.0f * llt[0]);
    if (tid < NT) tcs[tid] = tc[tid];
    // hoist coord staging (disjoint LDS; latency hides under Jacobi)
    for (int t = tid; t < NS*3; t += NTHR) scs[t] = sc[t];
    for (int t = tid; t < MS*3; t += NTHR) tscs[t] = tsc[t];
    __syncthreads();
    for (int idx = tid; idx < NT*NT; idx += NTHR) {
        int i = idx / NT, jj = idx - i*NT;
        float dt = tcs[i] - tcs[jj];
        float v = expf(-dt*dt*ilt2);
        if (i == jj) v += JITTER;
        A2[0][i][jj] = v;
    }
    for (int idx = tid; idx < NT*44; idx += NTHR) {
        int jr = idx / 44, k = idx - jr*44;
        Vts[jr][k] = (jr == k) ? 1.0f : 0.0f;
    }
    __syncthreads();
    int wave = tid >> 6, lane = tid & 63;
    for (int rd = 0; rd < ROUNDS; ++rd) {
        int cur = rd & 1, nxt = cur ^ 1;
        float4* wp = prm[wave];
        if (lane < NT/2) jac_params(A2[cur], wp, lane, rd % (NT - 1));
        __builtin_amdgcn_wave_barrier();   // same-wave LDS in-order; pin compiler
        for (int t = tid; t < 600; t += NTHR) {
            if (t < 400) {
                int bi = t / 20, bj = t - bi*20;
                float4 Pi = wp[bi], Pj = wp[bj];
                int pi = __float_as_int(Pi.z), qi = __float_as_int(Pi.w);
                int pj = __float_as_int(Pj.z), qj = __float_as_int(Pj.w);
                float ci = Pi.x, si = Pi.y, cj = Pj.x, sj = Pj.y;
                float a00 = A2[cur][pi][pj], a01 = A2[cur][pi][qj];
                float a10 = A2[cur][qi][pj], a11 = A2[cur][qi][qj];
                float b00 = ci*a00 - si*a10, b01 = ci*a01 - si*a11;
                float b10 = si*a00 + ci*a10, b11 = si*a01 + ci*a11;
                A2[nxt][pi][pj] = cj*b00 - sj*b01; A2[nxt][pi][qj] = sj*b00 + cj*b01;
                A2[nxt][qi][pj] = cj*b10 - sj*b11; A2[nxt][qi][qj] = sj*b10 + cj*b11;
            } else {
                int u2 = t - 400;
                int pr = u2 / 10, ch = (u2 - pr*10) << 2;
                float4 P = wp[pr];
                int pj = __float_as_int(P.z), qj = __float_as_int(P.w);
                float c = P.x, s = P.y;
                float4 vp = *(float4*)&Vts[pj][ch];
                float4 vq = *(float4*)&Vts[qj][ch];
                float4 np, nq;
                np.x = c*vp.x - s*vq.x; nq.x = s*vp.x + c*vq.x;
                np.y = c*vp.y - s*vq.y; nq.y = s*vp.y + c*vq.y;
                np.z = c*vp.z - s*vq.z; nq.z = s*vp.z + c*vq.z;
                np.w = c*vp.w - s*vq.w; nq.w = s*vp.w + c*vq.w;
                *(float4*)&Vts[pj][ch] = np;
                *(float4*)&Vts[qj][ch] = nq;
            }
        }
        __syncthreads();
    }
    const int fin = ROUNDS & 1;
    if (tid == 0) wtjs[0] = A2[fin][j][j];
    for (int s = tid; s < NS; s += NTHR) {
        const float4* va = (const float4*)&Vts[j][0];
        const float4* sa = (const float4*)&st[s*NT];
        float acc = 0.0f;
        #pragma unroll
        for (int c4 = 0; c4 < NT/4; ++c4) {
            float4 a = va[c4], b = sa[c4];
            acc += a.x*b.x + a.y*b.y + a.z*b.z + a.w*b.w;
        }
        gv[s] = acc;
    }
    if (tid < MT) {
        float ttv = ttc[tid];
        float acc = 0.0f;
        for (int t = 0; t < NT; ++t) {
            float dt = ttv - tcs[t];
            acc += expf(-dt*dt*ilt2) * Vts[j][t];
        }
        Acol[tid] = acc;
    }
    __syncthreads();

    // ---------- phase 2: build + rank-8 factor + scale + trsm ----------
    float* Mp   = (float*)(smem + OFF_MP);
    auto   Pr   = (float (*)[LDW])(smem + OFF_PR);
    float* invs = (float*)(smem + OFF_INVS);
    float* dvs  = (float*)(smem + OFF_DVS);
    float* qv   = (float*)(smem + OFF_QV);
    float* Rv   = (float*)(smem + OFF_RV);
    float wtj = wtjs[0];
    float nv = expf(lnv[0]);
    float ill2 = expf(-2.0f * lll[0]);
    float ile2 = expf(-2.0f * lle[0]);
    for (int idx = tid; idx < NS*LDW; idx += NTHR) {
        int r = idx / LDW, c = idx - r*LDW;
        int rbase = r & ~3;
        if (c < rbase) continue;
        float v;
        if (c < NS) {
            float d0 = scs[r*3+0] - scs[c*3+0];
            float d1 = scs[r*3+1] - scs[c*3+1];
            float d2 = scs[r*3+2] - scs[c*3+2];
            v = wtj * expf(-((d0*d0 + d1*d1)*ill2 + d2*d2*ile2));
            if (c == r) v += wtj * JITTER + nv;   // spatial jitter rides wtj
        } else if (c == NS) {
            v = gv[r];
        } else {
            v = 0.0f;
        }
        Mp[rs_off(r) + c - rbase] = v;
    }
    __syncthreads();
    for (int k0 = 0; k0 < NS - 1; k0 += 8) {
        int P = NS - k0; if (P > 8) P = 8;
        int W4 = (LDW - k0) >> 2;
        // phase A (single wave): redundant 8x8 elimination + chunk pre-elim -> Pr
        if (tid < W4) {
            int off[8];
            #pragma unroll
            for (int i = 0; i < 8; ++i)
                off[i] = (i < P) ? (rs_off(k0 + i) - ((i >= 4) ? 4 : 0)) : 0;
            float Bm[8][8];
            #pragma unroll
            for (int i = 0; i < 8; ++i) {
                #pragma unroll
                for (int c = 0; c < 8; ++c)
                    Bm[i][c] = (i < P && c >= i) ? Mp[off[i] + c]
                                                 : ((c == i) ? 1.0f : 0.0f);
            }
            float Lf[8][8]; float iv[8];
            #pragma unroll
            for (int k = 0; k < 8; ++k) {
                iv[k] = 1.0f / Bm[k][k];
                #pragma unroll
                for (int i = k + 1; i < 8; ++i) {
                    float l = Bm[k][i] * iv[k];
                    Lf[i][k] = l;
                    #pragma unroll
                    for (int c = i; c < 8; ++c) Bm[i][c] -= l * Bm[k][c];
                }
            }
            if (tid == 0) {
                #pragma unroll
                for (int i = 0; i < 8; ++i) invs[i] = iv[i];
            }
            int C = tid << 2;
            float4 m[8];
            #pragma unroll
            for (int i = 0; i < 8; ++i) {
                bool ok = (i < P) && (i < 4 || C >= 4);
                m[i] = ok ? *(float4*)&Mp[off[i] + C] : make_float4(0,0,0,0);
            }
            #pragma unroll
            for (int i = 1; i < 8; ++i) {
                #pragma unroll
                for (int k = 0; k < i; ++k) {
                    float l = Lf[i][k];
                    m[i].x -= l*m[k].x; m[i].y -= l*m[k].y;
                    m[i].z -= l*m[k].z; m[i].w -= l*m[k].w;
                }
            }
            #pragma unroll
            for (int i = 0; i < 8; ++i) *(float4*)&Pr[i][C] = m[i];
        }
        __syncthreads();
        // phase B: rank-8 trailing update, thread-per-row, contiguous f4 sweep
        for (int r = k0 + 1 + tid; r < NS; r += NTHR) {
            int rc = r - k0;
            float f[8];
            #pragma unroll
            for (int i = 0; i < 8; ++i)
                f[i] = (rc > i && i < P) ? Pr[i][rc] * invs[i] : 0.0f;
            int rbase = r & ~3;
            int ro = rs_off(r) - rbase;
            for (int C = rbase; C < LDW; C += 4) {
                int pc = C - k0;
                float4 v = *(float4*)&Mp[ro + C];
                #pragma unroll
                for (int i = 0; i < 8; ++i) {
                    float4 p = *(float4*)&Pr[i][pc];
                    v.x -= f[i]*p.x; v.y -= f[i]*p.y;
                    v.z -= f[i]*p.z; v.w -= f[i]*p.w;
                }
                *(float4*)&Mp[ro + C] = v;
            }
        }
        __syncthreads();
    }
    // scale in place: diag slot = 1/d, cols>r (incl. RHS col 150 -> y) *= 1/d
    for (int r = tid; r < NS; r += NTHR)
        dvs[r] = rsqrtf(Mp[rs_off(r) + r - (r & ~3)]);
    __syncthreads();
    for (int idx = tid; idx < NS*LDW; idx += NTHR) {
        int r = idx / LDW, c = idx - r*LDW;
        int rbase = r & ~3;
        if (c < rbase) continue;
        int t = rs_off(r) + c - rbase;
        float dvr = dvs[r];
        if (c == r) Mp[t] = dvr;
        else if (c > r) Mp[t] *= dvr;
    }
    __syncthreads();
    // fused trsm: thread-per-test-column, u[] in registers (152 w/ zero tail)
    if (tid < MS) {
        float tx = tscs[tid*3+0], ty = tscs[tid*3+1], tz = tscs[tid*3+2];
        float u[LDW];
        #pragma unroll
        for (int k = 0; k < NS; ++k) {
            float d0 = tx - scs[k*3+0];
            float d1 = ty - scs[k*3+1];
            float d2 = tz - scs[k*3+2];
            u[k] = expf(-((d0*d0 + d1*d1)*ill2 + d2*d2*ile2));
        }
        u[150] = 0.0f; u[151] = 0.0f;
        float qa = 0.0f, ra = 0.0f;
        #pragma unroll
        for (int k = 0; k < NS; ++k) {
            const int base = rs_off(k) - (k & ~3);
            float uk = u[k] * Mp[base + k];     // diag slot = 1/d
            qa += uk * uk;
            ra += uk * Mp[base + 150];          // scaled RHS = y_k
            const int kp = k + 1;
            const int ka = (kp + 3) & ~3;
            #pragma unroll
            for (int t = kp; t < ((ka < NS) ? ka : NS); ++t)
                u[t] -= Mp[base + t] * uk;
            #pragma unroll
            for (int t = ka; t < NS; t += 4) {
                float4 w = *(const float4*)&Mp[base + t];
                u[t+0] -= w.x * uk; u[t+1] -= w.y * uk;
                u[t+2] -= w.z * uk; u[t+3] -= w.w * uk;
            }
        }
        qv[tid] = qa;
        Rv[tid] = ra;
    }
    __syncthreads();

    // ---------- phase 3: atomic rank-1 accumulation into out ----------
    float sigv = expf(lsv[0]);
    for (int idx = tid; idx < MS*MT; idx += NTHR) {
        int is = idx / MT, it = idx - is*MT;
        float a = Acol[it];
        atomicAdd(&out[idx], a * Rv[is]);
        float c2 = -a * a * qv[is];
        if (j == 0) c2 += sigv;
        atomicAdd(&out[MS*MT + idx], c2);
    }
}

extern "C" void kernel_launch(void* const* d_in, const int* in_sizes, int n_in,
                              void* d_out, int out_size, void* d_ws, size_t ws_size,
                              hipStream_t stream) {
    const float* sc  = (const float*)d_in[0];   // 150x3
    const float* tc  = (const float*)d_in[1];   // 40x1
    const float* st  = (const float*)d_in[2];   // 150x40
    const float* tsc = (const float*)d_in[3];   // 200x3
    const float* ttc = (const float*)d_in[4];   // 30x1
    const float* lll = (const float*)d_in[5];
    const float* lle = (const float*)d_in[6];
    const float* llt = (const float*)d_in[7];
    const float* lnv = (const float*)d_in[8];
    const float* lsv = (const float*)d_in[9];
    float* out = (float*)d_out;

    hipMemsetAsync(out, 0, (size_t)out_size * sizeof(float), stream);
    hipLaunchKernelGGL(gp_block, dim3(NT), dim3(NTHR), 0, stream,
                       sc, tc, st, tsc, ttc, lll, lle, llt, lnv, lsv, out);
}